// Round 6
// baseline (147.755 us; speedup 1.0000x reference)
//
#include <hip/hip_runtime.h>
#include <hip/hip_bf16.h>
#include <stdint.h>
#include <stddef.h>

// ---------------------------------------------------------------------------
// ResAttnBlock: GroupNorm -> QKV -> full spatial attention -> proj -> residual
// B=32, C=256, S=32 (P=1024 positions), 32 groups of 8 channels.
// All GEMM-shaped work on v_mfma_f32_16x16x32_bf16; fp32 accumulate.
// ---------------------------------------------------------------------------

typedef float  f32x4  __attribute__((ext_vector_type(4)));
typedef __bf16 bf16x8 __attribute__((ext_vector_type(8)));
typedef __bf16 bf16x4 __attribute__((ext_vector_type(4)));

#define DEVI static __device__ __forceinline__

DEVI f32x4 mfma16(bf16x8 a, bf16x8 b, f32x4 c) {
  return __builtin_amdgcn_mfma_f32_16x16x32_bf16(a, b, c, 0, 0, 0);
}

DEVI f32x4 zero4() { f32x4 z = {0.f, 0.f, 0.f, 0.f}; return z; }

typedef const __attribute__((address_space(1))) void* gas_cvp;
typedef __attribute__((address_space(3))) void*       las_vp;

DEVI void gl_lds16(const __bf16* g, __bf16* l) {
  // async global->LDS, 16B per lane; LDS dest = uniform base + lane*16
  __builtin_amdgcn_global_load_lds((gas_cvp)g, (las_vp)l, 16, 0, 0);
}

#define WAIT_VM(N) asm volatile("s_waitcnt vmcnt(" #N ")" ::: "memory")
DEVI void bar() {
  asm volatile("" ::: "memory");
  __builtin_amdgcn_s_barrier();
  asm volatile("" ::: "memory");
}

// ---------------------------------------------------------------------------
// Kernel 0: convert weights to bf16 (w_attn 768x256, w_proj 256x256)
// ---------------------------------------------------------------------------
__global__ __launch_bounds__(256) void cvt_weights(
    const float* __restrict__ wa, const float* __restrict__ wp,
    __bf16* __restrict__ wab, __bf16* __restrict__ wpb) {
  const int i = blockIdx.x * 256 + threadIdx.x;
  if (i < 196608) {
    wab[i] = (__bf16)wa[i];
  } else {
    const int j = i - 196608;
    if (j < 65536) wpb[j] = (__bf16)wp[j];
  }
}

// ---------------------------------------------------------------------------
// Kernel 1: fused GroupNorm (stats + apply + transpose), single x pass.
// One block per (b,g): group = 8192 contiguous floats (8 ch x 1024 pos).
// ---------------------------------------------------------------------------
__global__ __launch_bounds__(256) void gn_fused(
    const float* __restrict__ x, const float* __restrict__ gamma,
    const float* __restrict__ beta, __bf16* __restrict__ h) {
  __shared__ __align__(16) float xs[8192];
  __shared__ float redS[4], redSS[4];
  const int bg = blockIdx.x;           // b*32+g
  const int b = bg >> 5, g = bg & 31;
  const int tid = threadIdx.x;
  const float* base = x + (size_t)bg * 8192;
  float s = 0.f, ss = 0.f;
#pragma unroll
  for (int it = 0; it < 8; ++it) {
    const int i = it * 256 + tid;      // f32x4 chunk index
    f32x4 v = *(const f32x4*)(base + i * 4);
    *(f32x4*)(xs + i * 4) = v;
    s  += v[0] + v[1] + v[2] + v[3];
    ss += v[0]*v[0] + v[1]*v[1] + v[2]*v[2] + v[3]*v[3];
  }
#pragma unroll
  for (int m = 1; m < 64; m <<= 1) {
    s  += __shfl_xor(s,  m, 64);
    ss += __shfl_xor(ss, m, 64);
  }
  const int lane = tid & 63, wave = tid >> 6;
  if (lane == 0) { redS[wave] = s; redSS[wave] = ss; }
  __syncthreads();
  const float S  = redS[0] + redS[1] + redS[2] + redS[3];
  const float SS = redSS[0] + redSS[1] + redSS[2] + redSS[3];
  const float mu = S * (1.f / 8192.f);
  const float rstd = rsqrtf(SS * (1.f / 8192.f) - mu * mu + 1e-5f);
  float ga[8], be[8];
#pragma unroll
  for (int j = 0; j < 8; ++j) {
    const int c = g * 8 + j;
    ga[j] = gamma[c] * rstd;
    be[j] = beta[c] - mu * ga[j];
  }
  __bf16* hb = h + ((size_t)b << 18) + g * 8;   // h[b][p][c]
#pragma unroll
  for (int it = 0; it < 4; ++it) {
    const int p = it * 256 + tid;
    bf16x8 o8;
#pragma unroll
    for (int j = 0; j < 8; ++j)
      o8[j] = (__bf16)(xs[j * 1024 + p] * ga[j] + be[j]);
    *(bf16x8*)(hb + ((size_t)p << 8)) = o8;
  }
}

// ---------------------------------------------------------------------------
// Full-K GEMM core: C(128x128) = A(128x256) * Bt(128x256)^T, single stage.
// Both full-K tiles (64KB each) staged at once -> exactly ONE barrier/drain
// per block (K=256 is short; the BK=64 loop paid 8 drains). 4 waves (2x2),
// each 64x64 = 4x4 frags; 128 MFMA/wave straight after the barrier.
// ---------------------------------------------------------------------------
DEVI void gemm_full(const __bf16* __restrict__ A0, const __bf16* __restrict__ B0,
                    __bf16* lA, __bf16* lB, int lane, int wave, f32x4 acc[4][4]) {
  const int wm = (wave >> 1) * 64;
  const int wn = (wave & 1) * 64;
  const int r15 = lane & 15, lg = lane >> 4;
#pragma unroll
  for (int i = 0; i < 4; ++i)
#pragma unroll
    for (int j = 0; j < 4; ++j) acc[i][j] = zero4();

  // stage [128][256] tiles: 4096 16B-chunks each, 16 per thread per array,
  // pre-swizzled source so fragment ds_read_b128s are spread across banks
#pragma unroll
  for (int it = 0; it < 16; ++it) {
    const int qch = it * 256 + wave * 64 + lane;
    const int row = qch >> 5, c32 = qch & 31;    // [128 rows][32 chunks]
    const int src = row * 256 + ((c32 ^ (row & 7)) << 3);
    gl_lds16(A0 + src, lA + (size_t)(it * 256 + wave * 64) * 8);
    gl_lds16(B0 + src, lB + (size_t)(it * 256 + wave * 64) * 8);
  }
  __syncthreads();  // vmcnt(0) + barrier: whole K extent resident
#pragma unroll
  for (int kk = 0; kk < 8; ++kk) {
    bf16x8 af[4], bfr[4];
#pragma unroll
    for (int i = 0; i < 4; ++i) {
      const int row = wm + i * 16 + r15;
      af[i] = *(const bf16x8*)((const char*)lA + row * 512 +
                               (((kk * 4 + lg) ^ (row & 7)) << 4));
    }
#pragma unroll
    for (int j = 0; j < 4; ++j) {
      const int row = wn + j * 16 + r15;
      bfr[j] = *(const bf16x8*)((const char*)lB + row * 512 +
                                (((kk * 4 + lg) ^ (row & 7)) << 4));
    }
#pragma unroll
    for (int i = 0; i < 4; ++i)
#pragma unroll
      for (int j = 0; j < 4; ++j) acc[i][j] = mfma16(af[i], bfr[j], acc[i][j]);
  }
}

// ---------------------------------------------------------------------------
// Kernel 3: QKV GEMM. h(32768x256) @ w_attn(768x256)^T + bias.
// q scaled by log2e/sqrt(C); v written transposed: v_t[b][d][p].
// ---------------------------------------------------------------------------
__global__ __launch_bounds__(256, 1) void qkv_gemm(
    const __bf16* __restrict__ h, const __bf16* __restrict__ wab,
    const float* __restrict__ b_attn,
    __bf16* __restrict__ q, __bf16* __restrict__ k, __bf16* __restrict__ vt) {
  extern __shared__ __align__(16) char gsm[];    // 131072 B
  __bf16* lA = (__bf16*)gsm;                     // [128][256] 64KB
  __bf16* lB = (__bf16*)(gsm + 65536);           // [128][256] 64KB
  const int nt = blockIdx.x, mt = blockIdx.y;
  const int tid = threadIdx.x, lane = tid & 63, wave = tid >> 6;
  f32x4 acc[4][4];
  gemm_full(h + (size_t)mt * 128 * 256, wab + (size_t)nt * 128 * 256,
            lA, lB, lane, wave, acc);

  const int wm = (wave >> 1) * 64, wn = (wave & 1) * 64;
  const int r15 = lane & 15, lg = lane >> 4;
  const int sec = nt >> 1;  // 0=q, 1=k, 2=v (tile never straddles sections)
  const float QS = 0.0625f * 1.44269504088896340736f;  // (1/sqrt(256))*log2(e)
#pragma unroll
  for (int j = 0; j < 4; ++j) {
    const int ng = nt * 128 + wn + j * 16 + r15;
    const float bias = b_attn[ng];
    const int c = ng & 255;
#pragma unroll
    for (int i = 0; i < 4; ++i) {
      const int mbase = mt * 128 + wm + i * 16 + lg * 4;
      if (sec == 0) {
#pragma unroll
        for (int r = 0; r < 4; ++r)
          q[(size_t)(mbase + r) * 256 + c] = (__bf16)((acc[i][j][r] + bias) * QS);
      } else if (sec == 1) {
#pragma unroll
        for (int r = 0; r < 4; ++r)
          k[(size_t)(mbase + r) * 256 + c] = (__bf16)(acc[i][j][r] + bias);
      } else {
        const int b = mbase >> 10, p = mbase & 1023;
        bf16x4 pk;
#pragma unroll
        for (int r = 0; r < 4; ++r) pk[r] = (__bf16)(acc[i][j][r] + bias);
        *(bf16x4*)(vt + (((size_t)(b * 256 + c)) << 10) + p) = pk;
      }
    }
  }
}

// ---------------------------------------------------------------------------
// Kernel 4: flash attention. Grid 256 (1 block/CU), 4 waves x 32 q-rows.
// m=32/wave halves the dominant cost (cross-wave-redundant LDS streaming of
// K/V tiles: 528 -> 264 ds_read_b128 per CU-iter). VGPR ~280 fits the
// 512-reg budget at 1 wave/SIMD (launch_bounds(256,1)). KVBLK=64 double-
// buffered K/V; counted vmcnt(16): next tile's 16 loads/thread stay in
// flight across compute. Swapped QK^T/PV, in-reg softmax, defer-rescale.
// ---------------------------------------------------------------------------
__global__ __launch_bounds__(256, 1) void attn(
    const __bf16* __restrict__ q, const __bf16* __restrict__ k,
    const __bf16* __restrict__ vt, __bf16* __restrict__ o) {
  extern __shared__ __align__(16) char smem[];   // 147456 B
  // layout: K0 @0, K1 @32768, V0 @65536, V1 @98304, P @131072 (4KB/wave)

  const int bid = blockIdx.x;
  const int xcd = bid & 7, sub = bid >> 3;       // sub 0..31
  const int b = xcd * 4 + (sub & 3);             // same-b blocks share an XCD
  const int qt = sub >> 2;                       // 0..7
  const int tid = threadIdx.x, lane = tid & 63, wave = tid >> 6;
  const int r15 = lane & 15, lg = lane >> 4, rs7 = r15 & 7;
  const int m0 = qt * 128 + wave * 32;
  char* P = smem + 131072 + wave * 4096;         // per-wave [32 q][64 kv] bf16 swz

  const __bf16* kb = k  + ((size_t)b << 18);
  const __bf16* vb = vt + ((size_t)b << 18);

  // Q fragments in registers: 2 q-halves x 8 k-chunks (64 VGPR)
  const __bf16* qb = q + (((size_t)(b * 1024 + m0)) << 8);
  bf16x8 qf[2][8];
#pragma unroll
  for (int qh = 0; qh < 2; ++qh)
#pragma unroll
    for (int kc = 0; kc < 8; ++kc)
      qf[qh][kc] = *(const bf16x8*)(qb + (size_t)(qh * 16 + r15) * 256 + kc * 32 + lg * 8);

  f32x4 po[16][2];   // O^T: po[df][qh][r] = O[q=qh*16+r15][d=df*16+lg*4+r]
#pragma unroll
  for (int d = 0; d < 16; ++d)
#pragma unroll
    for (int qh = 0; qh < 2; ++qh) po[d][qh] = zero4();
  float mrun[2] = {-1e30f, -1e30f}, lrun[2] = {0.f, 0.f};

  // staging: 2048 16B-chunks per tile, 8 per thread, pre-swizzled source
  auto stageK = [&](int n0, int buf) {
    __bf16* dst = (__bf16*)(smem + buf * 32768);
#pragma unroll
    for (int it = 0; it < 8; ++it) {
      const int qch = it * 256 + tid;            // [64 rows][32 chunks]
      const int row = qch >> 5, c32 = qch & 31;
      gl_lds16(kb + (size_t)(n0 + row) * 256 + ((c32 ^ (row & 7)) << 3),
               dst + (size_t)(it * 256 + wave * 64) * 8);
    }
  };
  auto stageV = [&](int n0, int buf) {
    __bf16* dst = (__bf16*)(smem + 65536 + buf * 32768);
#pragma unroll
    for (int it = 0; it < 8; ++it) {
      const int qch = it * 256 + tid;            // [256 rows][8 chunks]
      const int row = qch >> 3, c8 = qch & 7;
      gl_lds16(vb + ((size_t)row << 10) + n0 + ((c8 ^ (row & 7)) << 3),
               dst + (size_t)(it * 256 + wave * 64) * 8);
    }
  };

  stageK(0, 0);
  stageV(0, 0);

  for (int kv = 0; kv < 16; ++kv) {
    const int cur = kv & 1;
    const char* lK = (const char*)smem + cur * 32768;
    const char* lV = (const char*)smem + 65536 + cur * 32768;
    if (kv < 15) {
      stageK((kv + 1) * 64, cur ^ 1);
      stageV((kv + 1) * 64, cur ^ 1);
      WAIT_VM(16);    // tile-kv's 16 loads (issued last iter) have landed
    } else {
      WAIT_VM(0);
    }
    bar();            // all waves: tile kv resident

    // ---- swapped QK^T: S^T(64x32) = K(64x256) x Q(32x256)^T ----
    f32x4 s[2][4];
#pragma unroll
    for (int qh = 0; qh < 2; ++qh)
#pragma unroll
      for (int j = 0; j < 4; ++j) s[qh][j] = zero4();
#pragma unroll
    for (int kc = 0; kc < 8; ++kc) {
      bf16x8 kf[4];
#pragma unroll
      for (int j = 0; j < 4; ++j)
        kf[j] = *(const bf16x8*)(lK + (j * 16 + r15) * 512 +
                                 (((kc * 4 + lg) ^ rs7) << 4));
#pragma unroll
      for (int qh = 0; qh < 2; ++qh)
#pragma unroll
        for (int j = 0; j < 4; ++j) s[qh][j] = mfma16(kf[j], qf[qh][kc], s[qh][j]);
    }
    // lane holds S[kv=j*16+lg*4+r][q=qh*16+r15]
    // ---- online softmax per q-half: in-reg reduce + 2 shfl steps ----
    bf16x4 pk[2][4];
#pragma unroll
    for (int qh = 0; qh < 2; ++qh) {
      float pmax = s[qh][0][0];
#pragma unroll
      for (int j = 0; j < 4; ++j)
#pragma unroll
        for (int r = 0; r < 4; ++r) pmax = fmaxf(pmax, s[qh][j][r]);
      pmax = fmaxf(pmax, __shfl_xor(pmax, 16, 64));
      pmax = fmaxf(pmax, __shfl_xor(pmax, 32, 64));
      if (!__all(pmax <= mrun[qh] + 8.f)) {  // defer-rescale: P bounded by 2^8
        const float mn = fmaxf(mrun[qh], pmax);
        const float scl = exp2f(mrun[qh] - mn);
        mrun[qh] = mn;
        lrun[qh] *= scl;
#pragma unroll
        for (int d = 0; d < 16; ++d) po[d][qh] *= scl;
      }
      float psum = 0.f;
#pragma unroll
      for (int j = 0; j < 4; ++j)
#pragma unroll
        for (int r = 0; r < 4; ++r) {
          const float pv = exp2f(s[qh][j][r] - mrun[qh]);
          psum += pv;
          pk[qh][j][r] = (__bf16)pv;
        }
      psum += __shfl_xor(psum, 16, 64);
      psum += __shfl_xor(psum, 32, 64);
      lrun[qh] += psum;
    }
    // ---- P^T -> per-wave LDS: row=q-row, col=kv (packed 8B writes) ----
#pragma unroll
    for (int qh = 0; qh < 2; ++qh)
#pragma unroll
      for (int j = 0; j < 4; ++j)
        *(bf16x4*)(P + (qh * 16 + r15) * 128 + ((j * 32 + lg * 8) ^ (rs7 << 4))) =
            pk[qh][j];
    // ---- swapped PV: O^T(256x32) += V^T(256x64) x P(32x64)^T ----
#pragma unroll
    for (int kk = 0; kk < 2; ++kk) {
      bf16x8 pb[2];
#pragma unroll
      for (int qh = 0; qh < 2; ++qh)
        pb[qh] = *(const bf16x8*)(P + (qh * 16 + r15) * 128 +
                                  (((kk * 4 + lg) ^ rs7) << 4));
#pragma unroll
      for (int df = 0; df < 16; ++df) {
        const bf16x8 vf = *(const bf16x8*)(lV + (df * 16 + r15) * 128 +
                                           (((kk * 4 + lg) ^ rs7) << 4));
#pragma unroll
        for (int qh = 0; qh < 2; ++qh) po[df][qh] = mfma16(vf, pb[qh], po[df][qh]);
      }
    }
    bar();            // all waves done reading buf[cur]; next iter restages it
  }
  // ---- epilogue: O/l, 4 consecutive d per reg quad -> bf16x4 stores ----
  const float inv0 = 1.f / lrun[0], inv1 = 1.f / lrun[1];
#pragma unroll
  for (int qh = 0; qh < 2; ++qh) {
    const float inv = qh ? inv1 : inv0;
    __bf16* ob = o + (((size_t)(b * 1024 + m0 + qh * 16 + r15)) << 8);
#pragma unroll
    for (int df = 0; df < 16; ++df) {
      bf16x4 t;
#pragma unroll
      for (int r = 0; r < 4; ++r) t[r] = (__bf16)(po[df][qh][r] * inv);
      *(bf16x4*)(ob + df * 16 + lg * 4) = t;
    }
  }
}

// ---------------------------------------------------------------------------
// Kernel 5: proj GEMM + bias + residual, writes fp32 out in (B,C,S,S).
// ---------------------------------------------------------------------------
__global__ __launch_bounds__(256, 1) void proj_gemm(
    const __bf16* __restrict__ o, const __bf16* __restrict__ wpb,
    const float* __restrict__ b_proj, const float* __restrict__ x,
    float* __restrict__ out) {
  extern __shared__ __align__(16) char gsm[];    // 131072 B
  __bf16* lA = (__bf16*)gsm;
  __bf16* lB = (__bf16*)(gsm + 65536);
  const int nt = blockIdx.x, mt = blockIdx.y;
  const int tid = threadIdx.x, lane = tid & 63, wave = tid >> 6;
  f32x4 acc[4][4];
  gemm_full(o + (size_t)mt * 128 * 256, wpb + (size_t)nt * 128 * 256,
            lA, lB, lane, wave, acc);

  const int wm = (wave >> 1) * 64, wn = (wave & 1) * 64;
  const int r15 = lane & 15, lg = lane >> 4;
#pragma unroll
  for (int j = 0; j < 4; ++j) {
    const int c = nt * 128 + wn + j * 16 + r15;
    const float bias = b_proj[c];
#pragma unroll
    for (int i = 0; i < 4; ++i) {
      const int mbase = mt * 128 + wm + i * 16 + lg * 4;
      const int b = mbase >> 10, p = mbase & 1023;
      const size_t off = (((size_t)(b * 256 + c)) << 10) + p;
      f32x4 xv = *(const f32x4*)(x + off);
      f32x4 r = acc[i][j];
      r = r + xv;
      r = r + bias;
      *(f32x4*)(out + off) = r;
    }
  }
}

// ---------------------------------------------------------------------------
// Launcher
// ---------------------------------------------------------------------------
extern "C" void kernel_launch(void* const* d_in, const int* in_sizes, int n_in,
                              void* d_out, int out_size, void* d_ws, size_t ws_size,
                              hipStream_t stream) {
  const float* x      = (const float*)d_in[0];
  // d_in[1] = t_embd (unused by reference)
  const float* gamma  = (const float*)d_in[2];
  const float* beta   = (const float*)d_in[3];
  const float* w_attn = (const float*)d_in[4];
  const float* b_attn = (const float*)d_in[5];
  const float* w_proj = (const float*)d_in[6];
  const float* b_proj = (const float*)d_in[7];
  float* out = (float*)d_out;

  char* ws = (char*)d_ws;
  __bf16* h   = (__bf16*)(ws);                          // 16MB, reused as o
  __bf16* qb  = (__bf16*)(ws + ((size_t)16 << 20));     // 16MB
  __bf16* kb  = (__bf16*)(ws + ((size_t)32 << 20));     // 16MB
  __bf16* vtb = (__bf16*)(ws + ((size_t)48 << 20));     // 16MB, [B][C][P]
  __bf16* wab = (__bf16*)(ws + ((size_t)64 << 20));     // 384KB
  __bf16* wpb = wab + 196608;                           // 128KB

  cvt_weights<<<1024, 256, 0, stream>>>(w_attn, w_proj, wab, wpb);
  gn_fused<<<1024, 256, 0, stream>>>(x, gamma, beta, h);
  qkv_gemm<<<dim3(6, 256), 256, 131072, stream>>>(h, wab, b_attn, qb, kb, vtb);
  attn<<<256, 256, 147456, stream>>>(qb, kb, vtb, h /* o reuses h */);
  proj_gemm<<<dim3(2, 256), 256, 131072, stream>>>(h, wpb, b_proj, x, out);
}

// Round 7
// 128.592 us; speedup vs baseline: 1.1490x; 1.1490x over previous
//
#include <hip/hip_runtime.h>
#include <hip/hip_bf16.h>
#include <stdint.h>
#include <stddef.h>

// ---------------------------------------------------------------------------
// ResAttnBlock: GroupNorm -> QKV -> full spatial attention -> proj -> residual
// B=32, C=256, S=32 (P=1024 positions), 32 groups of 8 channels.
// All GEMM-shaped work on v_mfma_f32_16x16x32_bf16; fp32 accumulate.
// ---------------------------------------------------------------------------

typedef float  f32x4  __attribute__((ext_vector_type(4)));
typedef __bf16 bf16x8 __attribute__((ext_vector_type(8)));
typedef __bf16 bf16x4 __attribute__((ext_vector_type(4)));

#define DEVI static __device__ __forceinline__

DEVI f32x4 mfma16(bf16x8 a, bf16x8 b, f32x4 c) {
  return __builtin_amdgcn_mfma_f32_16x16x32_bf16(a, b, c, 0, 0, 0);
}

DEVI f32x4 zero4() { f32x4 z = {0.f, 0.f, 0.f, 0.f}; return z; }

typedef const __attribute__((address_space(1))) void* gas_cvp;
typedef __attribute__((address_space(3))) void*       las_vp;

DEVI void gl_lds16(const __bf16* g, __bf16* l) {
  // async global->LDS, 16B per lane; LDS dest = uniform base + lane*16
  __builtin_amdgcn_global_load_lds((gas_cvp)g, (las_vp)l, 16, 0, 0);
}

#define WAIT_VM(N) asm volatile("s_waitcnt vmcnt(" #N ")" ::: "memory")
DEVI void bar() {
  asm volatile("" ::: "memory");
  __builtin_amdgcn_s_barrier();
  asm volatile("" ::: "memory");
}

// ---------------------------------------------------------------------------
// Kernel 0: convert weights to bf16 (w_attn 768x256, w_proj 256x256)
// ---------------------------------------------------------------------------
__global__ __launch_bounds__(256) void cvt_weights(
    const float* __restrict__ wa, const float* __restrict__ wp,
    __bf16* __restrict__ wab, __bf16* __restrict__ wpb) {
  const int i = blockIdx.x * 256 + threadIdx.x;
  if (i < 196608) {
    wab[i] = (__bf16)wa[i];
  } else {
    const int j = i - 196608;
    if (j < 65536) wpb[j] = (__bf16)wp[j];
  }
}

// ---------------------------------------------------------------------------
// Kernel 1: fused GroupNorm (stats + apply + transpose), single x pass.
// One block per (b,g): group = 8192 contiguous floats (8 ch x 1024 pos).
// ---------------------------------------------------------------------------
__global__ __launch_bounds__(256) void gn_fused(
    const float* __restrict__ x, const float* __restrict__ gamma,
    const float* __restrict__ beta, __bf16* __restrict__ h) {
  __shared__ __align__(16) float xs[8192];
  __shared__ float redS[4], redSS[4];
  const int bg = blockIdx.x;           // b*32+g
  const int b = bg >> 5, g = bg & 31;
  const int tid = threadIdx.x;
  const float* base = x + (size_t)bg * 8192;
  float s = 0.f, ss = 0.f;
#pragma unroll
  for (int it = 0; it < 8; ++it) {
    const int i = it * 256 + tid;      // f32x4 chunk index
    f32x4 v = *(const f32x4*)(base + i * 4);
    *(f32x4*)(xs + i * 4) = v;
    s  += v[0] + v[1] + v[2] + v[3];
    ss += v[0]*v[0] + v[1]*v[1] + v[2]*v[2] + v[3]*v[3];
  }
#pragma unroll
  for (int m = 1; m < 64; m <<= 1) {
    s  += __shfl_xor(s,  m, 64);
    ss += __shfl_xor(ss, m, 64);
  }
  const int lane = tid & 63, wave = tid >> 6;
  if (lane == 0) { redS[wave] = s; redSS[wave] = ss; }
  __syncthreads();
  const float S  = redS[0] + redS[1] + redS[2] + redS[3];
  const float SS = redSS[0] + redSS[1] + redSS[2] + redSS[3];
  const float mu = S * (1.f / 8192.f);
  const float rstd = rsqrtf(SS * (1.f / 8192.f) - mu * mu + 1e-5f);
  float ga[8], be[8];
#pragma unroll
  for (int j = 0; j < 8; ++j) {
    const int c = g * 8 + j;
    ga[j] = gamma[c] * rstd;
    be[j] = beta[c] - mu * ga[j];
  }
  __bf16* hb = h + ((size_t)b << 18) + g * 8;   // h[b][p][c]
#pragma unroll
  for (int it = 0; it < 4; ++it) {
    const int p = it * 256 + tid;
    bf16x8 o8;
#pragma unroll
    for (int j = 0; j < 8; ++j)
      o8[j] = (__bf16)(xs[j * 1024 + p] * ga[j] + be[j]);
    *(bf16x8*)(hb + ((size_t)p << 8)) = o8;
  }
}

// ---------------------------------------------------------------------------
// Shared GEMM core: C(128x128) = A(128xK=256) * Bt(128 rows x 256)^T
// 4 waves (2x2), each 64x64 = 4x4 frags. BK=64, 4 k-outer steps.
// 32KB LDS -> ~5 blocks/CU of TLP (the full-K variant killed this; reverted).
// ---------------------------------------------------------------------------
DEVI void gemm_core_k256(const __bf16* __restrict__ A0, const __bf16* __restrict__ B0,
                         __bf16* lA, __bf16* lB, int lane, int wave, f32x4 acc[4][4]) {
  const int wm = (wave >> 1) * 64;
  const int wn = (wave & 1) * 64;
  const int r15 = lane & 15, lg = lane >> 4;
#pragma unroll
  for (int i = 0; i < 4; ++i)
#pragma unroll
    for (int j = 0; j < 4; ++j) acc[i][j] = zero4();

  for (int ko = 0; ko < 4; ++ko) {
    // stage [128][64] tiles; chunk q = row*8 + c8 (16B chunks)
#pragma unroll
    for (int it = 0; it < 4; ++it) {
      const int q = wave * 256 + it * 64 + lane;
      const int row = q >> 3, c8 = q & 7;
      const int srcoff = row * 256 + ko * 64 + ((c8 ^ (row & 7)) << 3);
      gl_lds16(A0 + srcoff, lA + (size_t)(wave * 256 + it * 64) * 8);
      gl_lds16(B0 + srcoff, lB + (size_t)(wave * 256 + it * 64) * 8);
    }
    __syncthreads();  // drains vmcnt before LDS reads
#pragma unroll
    for (int kk = 0; kk < 2; ++kk) {
      bf16x8 af[4], bfr[4];
#pragma unroll
      for (int i = 0; i < 4; ++i) {
        const int row = wm + i * 16 + r15;
        af[i] = *(const bf16x8*)((const char*)lA + row * 128 +
                                 (((kk * 4 + lg) ^ (row & 7)) << 4));
      }
#pragma unroll
      for (int j = 0; j < 4; ++j) {
        const int row = wn + j * 16 + r15;
        bfr[j] = *(const bf16x8*)((const char*)lB + row * 128 +
                                  (((kk * 4 + lg) ^ (row & 7)) << 4));
      }
#pragma unroll
      for (int i = 0; i < 4; ++i)
#pragma unroll
        for (int j = 0; j < 4; ++j) acc[i][j] = mfma16(af[i], bfr[j], acc[i][j]);
    }
    __syncthreads();
  }
}

// ---------------------------------------------------------------------------
// Kernel 3: QKV GEMM. h(32768x256) @ w_attn(768x256)^T + bias.
// q scaled by log2e/sqrt(C); v written transposed: v_t[b][d][p].
// ---------------------------------------------------------------------------
__global__ __launch_bounds__(256) void qkv_gemm(
    const __bf16* __restrict__ h, const __bf16* __restrict__ wab,
    const float* __restrict__ b_attn,
    __bf16* __restrict__ q, __bf16* __restrict__ k, __bf16* __restrict__ vt) {
  __shared__ __align__(16) __bf16 lA[128 * 64], lB[128 * 64];
  const int nt = blockIdx.x, mt = blockIdx.y;
  const int tid = threadIdx.x, lane = tid & 63, wave = tid >> 6;
  f32x4 acc[4][4];
  gemm_core_k256(h + (size_t)mt * 128 * 256, wab + (size_t)nt * 128 * 256,
                 lA, lB, lane, wave, acc);

  const int wm = (wave >> 1) * 64, wn = (wave & 1) * 64;
  const int r15 = lane & 15, lg = lane >> 4;
  const int sec = nt >> 1;  // 0=q, 1=k, 2=v (tile never straddles sections)
  const float QS = 0.0625f * 1.44269504088896340736f;  // (1/sqrt(256))*log2(e)
#pragma unroll
  for (int j = 0; j < 4; ++j) {
    const int ng = nt * 128 + wn + j * 16 + r15;
    const float bias = b_attn[ng];
    const int c = ng & 255;
#pragma unroll
    for (int i = 0; i < 4; ++i) {
      const int mbase = mt * 128 + wm + i * 16 + lg * 4;
      if (sec == 0) {
#pragma unroll
        for (int r = 0; r < 4; ++r)
          q[(size_t)(mbase + r) * 256 + c] = (__bf16)((acc[i][j][r] + bias) * QS);
      } else if (sec == 1) {
#pragma unroll
        for (int r = 0; r < 4; ++r)
          k[(size_t)(mbase + r) * 256 + c] = (__bf16)(acc[i][j][r] + bias);
      } else {
        const int b = mbase >> 10, p = mbase & 1023;
        bf16x4 pk;
#pragma unroll
        for (int r = 0; r < 4; ++r) pk[r] = (__bf16)(acc[i][j][r] + bias);
        *(bf16x4*)(vt + (((size_t)(b * 256 + c)) << 10) + p) = pk;
      }
    }
  }
}

// ---------------------------------------------------------------------------
// Kernel 4: flash attention. Grid 512, 4 waves x 16 q-rows, 72KB LDS ->
// 2 INDEPENDENT blocks/CU: cross-block phase overlap (block A softmax VALU
// hides block B MFMA) that the single-block lockstep versions lacked.
// Single-buffered K/V with counted-vmcnt 3-barrier schedule: next-tile
// loads are issued right after the done-reading barrier and stay in
// flight across a full compute phase (never drained while useful).
// Swapped QK^T/PV, in-reg softmax, defer-rescale, setprio on MFMA.
// ---------------------------------------------------------------------------
__global__ __launch_bounds__(256, 2) void attn(
    const __bf16* __restrict__ q, const __bf16* __restrict__ k,
    const __bf16* __restrict__ vt, __bf16* __restrict__ o) {
  extern __shared__ __align__(16) char smem[];   // 73728 B
  // layout: lK @0 [64][256] 32KB swz, lV @32768 [256][64] 32KB swz,
  //         P @65536 + wave*2048 (per-wave [16 q][64 kv] bf16 swz)

  const int bid = blockIdx.x;
  const int xcd = bid & 7, sub = bid >> 3;       // sub 0..63
  const int b = xcd * 4 + (sub & 3);             // same-b blocks share an XCD
  const int qt = sub >> 2;                       // 0..15
  const int tid = threadIdx.x, lane = tid & 63, wave = tid >> 6;
  const int r15 = lane & 15, lg = lane >> 4, rs7 = r15 & 7;
  const int m0 = qt * 64 + wave * 16;
  char* P = smem + 65536 + wave * 2048;

  const __bf16* kb = k  + ((size_t)b << 18);
  const __bf16* vb = vt + ((size_t)b << 18);

  // Q fragments in registers: 8 k-chunks (32 VGPR); B-operand layout
  const __bf16* qb = q + (((size_t)(b * 1024 + m0)) << 8);
  bf16x8 qf[8];
#pragma unroll
  for (int kc = 0; kc < 8; ++kc)
    qf[kc] = *(const bf16x8*)(qb + ((size_t)r15) * 256 + kc * 32 + lg * 8);

  f32x4 po[16];   // O^T: po[df][r] = O[q=r15][d=df*16+lg*4+r]
#pragma unroll
  for (int d = 0; d < 16; ++d) po[d] = zero4();
  float mrun = -1e30f, lrun = 0.f;   // per-lane (q-row r15, replicated x4 lg)

  // staging: 2048 16B-chunks per tile, 8 per thread, pre-swizzled source
  auto stageK = [&](int n0) {
    __bf16* dst = (__bf16*)smem;
#pragma unroll
    for (int it = 0; it < 8; ++it) {
      const int qch = it * 256 + tid;            // [64 rows][32 chunks]
      const int row = qch >> 5, c32 = qch & 31;
      gl_lds16(kb + (size_t)(n0 + row) * 256 + ((c32 ^ (row & 7)) << 3),
               dst + (size_t)(it * 256 + wave * 64) * 8);
    }
  };
  auto stageV = [&](int n0) {
    __bf16* dst = (__bf16*)(smem + 32768);
#pragma unroll
    for (int it = 0; it < 8; ++it) {
      const int qch = it * 256 + tid;            // [256 rows][8 chunks]
      const int row = qch >> 3, c8 = qch & 7;
      gl_lds16(vb + ((size_t)row << 10) + n0 + ((c8 ^ (row & 7)) << 3),
               dst + (size_t)(it * 256 + wave * 64) * 8);
    }
  };

  stageK(0);
  stageV(0);

  const char* lK = (const char*)smem;
  const char* lV = (const char*)smem + 32768;

  for (int kv = 0; kv < 16; ++kv) {
    // top: outstanding = K(kv)[8] + V(kv)[8]; leave 8 -> K(kv) landed
    WAIT_VM(8);
    bar();          // all waves' K-writes visible

    // ---- swapped QK^T: S^T(64x16) = K(64x256) x Q(16x256)^T ----
    f32x4 s[4];
#pragma unroll
    for (int j = 0; j < 4; ++j) s[j] = zero4();
    __builtin_amdgcn_s_setprio(1);
#pragma unroll
    for (int kc = 0; kc < 8; ++kc) {
      bf16x8 kf[4];
#pragma unroll
      for (int j = 0; j < 4; ++j)
        kf[j] = *(const bf16x8*)(lK + (j * 16 + r15) * 512 +
                                 (((kc * 4 + lg) ^ rs7) << 4));
#pragma unroll
      for (int j = 0; j < 4; ++j) s[j] = mfma16(kf[j], qf[kc], s[j]);
    }
    __builtin_amdgcn_s_setprio(0);
    // lane holds S[kv=j*16+lg*4+r][qrow=r15] -> full column for one q-row
    // ---- online softmax: in-reg max/sum + 2 shfl steps ----
    float pmax = s[0][0];
#pragma unroll
    for (int j = 0; j < 4; ++j)
#pragma unroll
      for (int r = 0; r < 4; ++r) pmax = fmaxf(pmax, s[j][r]);
    pmax = fmaxf(pmax, __shfl_xor(pmax, 16, 64));
    pmax = fmaxf(pmax, __shfl_xor(pmax, 32, 64));
    if (!__all(pmax <= mrun + 8.f)) {   // defer-rescale: P bounded by 2^8
      const float mn = fmaxf(mrun, pmax);
      const float scl = exp2f(mrun - mn);
      mrun = mn;
      lrun *= scl;
#pragma unroll
      for (int d = 0; d < 16; ++d) po[d] *= scl;
    }
    float psum = 0.f;
    bf16x4 pk[4];
#pragma unroll
    for (int j = 0; j < 4; ++j)
#pragma unroll
      for (int r = 0; r < 4; ++r) {
        const float pv = exp2f(s[j][r] - mrun);
        psum += pv;
        pk[j][r] = (__bf16)pv;
      }
    psum += __shfl_xor(psum, 16, 64);
    psum += __shfl_xor(psum, 32, 64);
    lrun += psum;
    // ---- P^T -> per-wave LDS: row=q-row r15, col=kv (packed 8B writes) ----
#pragma unroll
    for (int j = 0; j < 4; ++j)
      *(bf16x4*)(P + r15 * 128 + ((j * 32 + lg * 8) ^ (rs7 << 4))) = pk[j];

    // V(kv) was issued a full iteration ago; K(kv+1) not yet issued, so this
    // drain stalls nothing useful.
    WAIT_VM(0);
    bar();          // all waves: done reading lK, V(kv) visible
    if (kv < 15) stageK((kv + 1) * 64);   // overwrite lK, hides under PV

    // ---- swapped PV: O^T(256x16) += V^T(256x64) x P(16x64)^T ----
    __builtin_amdgcn_s_setprio(1);
#pragma unroll
    for (int kk = 0; kk < 2; ++kk) {
      const bf16x8 pb =
          *(const bf16x8*)(P + r15 * 128 + (((kk * 4 + lg) ^ rs7) << 4));
#pragma unroll
      for (int df = 0; df < 16; ++df) {
        const bf16x8 vf = *(const bf16x8*)(lV + (df * 16 + r15) * 128 +
                                           (((kk * 4 + lg) ^ rs7) << 4));
        po[df] = mfma16(vf, pb, po[df]);
      }
    }
    __builtin_amdgcn_s_setprio(0);
    bar();          // all waves done reading lV
    if (kv < 15) stageV((kv + 1) * 64);   // hides under next QK^T
  }
  // ---- epilogue: O/l, 4 consecutive d per reg quad -> bf16x4 stores ----
  const float inv = 1.f / lrun;
  __bf16* ob = o + (((size_t)(b * 1024 + m0 + r15)) << 8);
#pragma unroll
  for (int df = 0; df < 16; ++df) {
    bf16x4 t;
#pragma unroll
    for (int r = 0; r < 4; ++r) t[r] = (__bf16)(po[df][r] * inv);
    *(bf16x4*)(ob + df * 16 + lg * 4) = t;
  }
}

// ---------------------------------------------------------------------------
// Kernel 5: proj GEMM + bias + residual, writes fp32 out in (B,C,S,S).
// ---------------------------------------------------------------------------
__global__ __launch_bounds__(256) void proj_gemm(
    const __bf16* __restrict__ o, const __bf16* __restrict__ wpb,
    const float* __restrict__ b_proj, const float* __restrict__ x,
    float* __restrict__ out) {
  __shared__ __align__(16) __bf16 lA[128 * 64], lB[128 * 64];
  const int nt = blockIdx.x, mt = blockIdx.y;
  const int tid = threadIdx.x, lane = tid & 63, wave = tid >> 6;
  f32x4 acc[4][4];
  gemm_core_k256(o + (size_t)mt * 128 * 256, wpb + (size_t)nt * 128 * 256,
                 lA, lB, lane, wave, acc);

  const int wm = (wave >> 1) * 64, wn = (wave & 1) * 64;
  const int r15 = lane & 15, lg = lane >> 4;
#pragma unroll
  for (int j = 0; j < 4; ++j) {
    const int c = nt * 128 + wn + j * 16 + r15;
    const float bias = b_proj[c];
#pragma unroll
    for (int i = 0; i < 4; ++i) {
      const int mbase = mt * 128 + wm + i * 16 + lg * 4;
      const int b = mbase >> 10, p = mbase & 1023;
      const size_t off = (((size_t)(b * 256 + c)) << 10) + p;
      f32x4 xv = *(const f32x4*)(x + off);
      f32x4 r = acc[i][j];
      r = r + xv;
      r = r + bias;
      *(f32x4*)(out + off) = r;
    }
  }
}

// ---------------------------------------------------------------------------
// Launcher
// ---------------------------------------------------------------------------
extern "C" void kernel_launch(void* const* d_in, const int* in_sizes, int n_in,
                              void* d_out, int out_size, void* d_ws, size_t ws_size,
                              hipStream_t stream) {
  const float* x      = (const float*)d_in[0];
  // d_in[1] = t_embd (unused by reference)
  const float* gamma  = (const float*)d_in[2];
  const float* beta   = (const float*)d_in[3];
  const float* w_attn = (const float*)d_in[4];
  const float* b_attn = (const float*)d_in[5];
  const float* w_proj = (const float*)d_in[6];
  const float* b_proj = (const float*)d_in[7];
  float* out = (float*)d_out;

  char* ws = (char*)d_ws;
  __bf16* h   = (__bf16*)(ws);                          // 16MB, reused as o
  __bf16* qb  = (__bf16*)(ws + ((size_t)16 << 20));     // 16MB
  __bf16* kb  = (__bf16*)(ws + ((size_t)32 << 20));     // 16MB
  __bf16* vtb = (__bf16*)(ws + ((size_t)48 << 20));     // 16MB, [B][C][P]
  __bf16* wab = (__bf16*)(ws + ((size_t)64 << 20));     // 384KB
  __bf16* wpb = wab + 196608;                           // 128KB

  cvt_weights<<<1024, 256, 0, stream>>>(w_attn, w_proj, wab, wpb);
  gn_fused<<<1024, 256, 0, stream>>>(x, gamma, beta, h);
  qkv_gemm<<<dim3(6, 256), 256, 0, stream>>>(h, wab, b_attn, qb, kb, vtb);
  attn<<<512, 256, 73728, stream>>>(qb, kb, vtb, h /* o reuses h */);
  proj_gemm<<<dim3(2, 256), 256, 0, stream>>>(h, wpb, b_proj, x, out);
}